// Round 8
// baseline (149.370 us; speedup 1.0000x reference)
//
#include <hip/hip_runtime.h>
#include <hip/hip_fp16.h>

// EdgeNetwork: out[e] = MLP(concat(x[s], x[t], vp[batch[s]])), 48->8->8->8->1,
// LayerNorm+tanh between layers.
//
// R8 structure:
//   node_pre (N threads): per-node layer-1 partials, mean-centered, fp16
//     tables ya/yb ([N,8] each, 1.6 MB -> L2-resident). h1 = ya'[s]+yb'[t]
//     is zero-mean -> LN1 skips the mean pass.
//   pack_kernel (1 thread): folds constants:
//     g*, be* scaled by K=2*log2(e)  (tanh arg feeds exp2 directly)
//     W2,W3,W4 -> -2*W ; b -> b + colsum(W)   (tanh = 1 - 2*rcp(exp2+1);
//     the "1" is absorbed into the next bias, "-2" into the next weights,
//     so matmuls consume raw rcp outputs)
//   edge_main: TWO edges per thread (independent chains interleaved ->
//     transcendental/gather latency of one chain hides under the other).
//     Layers 2/3 in packed fp16 (v_pk_fma_f16). R7 post-mortem: single
//     chain was latency-bound (VALUBusy fell 76->68 with flat time).

struct WPack {
    __half2 w2[32];            // -2*W2: w2[i*4+k] = pair (j=2k, 2k+1)
    __half2 w3[32];            // -2*W3
    __half2 b2p[4], b3p[4];    // b + colsum(W)
    __half2 g1p[4], be1p[4];   // g1*K, be1*K
    __half2 g2p[4], be2p[4];
    __half2 g3p[4], be3p[4];
    float w4[8];               // -2*W4
    float b4a;                 // b4 + sum(W4)
};

typedef __attribute__((ext_vector_type(8))) _Float16 h8;

#if __has_builtin(__builtin_amdgcn_exp2f)
#define EXP2F(x) __builtin_amdgcn_exp2f(x)
#else
#define EXP2F(x) exp2f(x)
#endif

#define K2LOG2E 2.8853900817779268f

__device__ __forceinline__ float fast_tanh(float v) {
    float e = __expf(2.0f * v);
    return fmaf(-2.0f, __builtin_amdgcn_rcpf(e + 1.0f), 1.0f);
}

// ---------------- Kernel A: per-node layer-1 partials (fp16, centered) -------
__global__ __launch_bounds__(256) void node_pre_kernel(
    const float* __restrict__ x,      // [N,16]
    const int* __restrict__ batch,    // [N]
    const float* __restrict__ vp,     // [64,16]
    const float* __restrict__ W1,     // [48,8]
    const float* __restrict__ b1,     // [8]
    h8* __restrict__ ya16,            // [N]
    h8* __restrict__ yb16,            // [N]
    int N)
{
    int n = blockIdx.x * blockDim.x + threadIdx.x;
    if (n >= N) return;

    const float4* px = reinterpret_cast<const float4*>(x) + (size_t)n * 4;
    float4 x0 = px[0], x1 = px[1], x2 = px[2], x3 = px[3];
    int g = batch[n];
    const float4* pv = reinterpret_cast<const float4*>(vp) + (size_t)g * 4;
    float4 v0 = pv[0], v1 = pv[1], v2 = pv[2], v3 = pv[3];

    float xs[16] = {x0.x, x0.y, x0.z, x0.w, x1.x, x1.y, x1.z, x1.w,
                    x2.x, x2.y, x2.z, x2.w, x3.x, x3.y, x3.z, x3.w};
    float vs[16] = {v0.x, v0.y, v0.z, v0.w, v1.x, v1.y, v1.z, v1.w,
                    v2.x, v2.y, v2.z, v2.w, v3.x, v3.y, v3.z, v3.w};

    float ya[8], yb[8];
#pragma unroll
    for (int j = 0; j < 8; ++j) { ya[j] = b1[j]; yb[j] = 0.0f; }

#pragma unroll
    for (int i = 0; i < 16; ++i) {
        float vx = xs[i];
        float vv = vs[i];
#pragma unroll
        for (int j = 0; j < 8; ++j) {
            ya[j] = fmaf(vx, W1[i * 8 + j], ya[j]);
            ya[j] = fmaf(vv, W1[(32 + i) * 8 + j], ya[j]);
            yb[j] = fmaf(vx, W1[(16 + i) * 8 + j], yb[j]);
        }
    }

    float mua = 0.0f, mub = 0.0f;
#pragma unroll
    for (int j = 0; j < 8; ++j) { mua += ya[j]; mub += yb[j]; }
    mua *= 0.125f; mub *= 0.125f;

    h8 va, vb;
#pragma unroll
    for (int j = 0; j < 8; ++j) {
        va[j] = (_Float16)(ya[j] - mua);
        vb[j] = (_Float16)(yb[j] - mub);
    }
    ya16[n] = va;
    yb16[n] = vb;
}

// ---------------- Kernel P: fold + pack constants (1 thread) -----------------
__global__ void pack_kernel(
    const float* __restrict__ W2, const float* __restrict__ b2,
    const float* __restrict__ W3, const float* __restrict__ b3,
    const float* __restrict__ g1, const float* __restrict__ be1,
    const float* __restrict__ g2, const float* __restrict__ be2,
    const float* __restrict__ g3, const float* __restrict__ be3,
    const float* __restrict__ W4, const float* __restrict__ b4,
    WPack* __restrict__ wp)
{
    if (threadIdx.x != 0 || blockIdx.x != 0) return;
#pragma unroll
    for (int t = 0; t < 32; ++t) {
        wp->w2[t] = __floats2half2_rn(-2.0f * W2[2 * t], -2.0f * W2[2 * t + 1]);
        wp->w3[t] = __floats2half2_rn(-2.0f * W3[2 * t], -2.0f * W3[2 * t + 1]);
    }
    float cs2[8], cs3[8];
#pragma unroll
    for (int j = 0; j < 8; ++j) {
        float s2 = 0.0f, s3 = 0.0f;
#pragma unroll
        for (int i = 0; i < 8; ++i) { s2 += W2[i * 8 + j]; s3 += W3[i * 8 + j]; }
        cs2[j] = b2[j] + s2;
        cs3[j] = b3[j] + s3;
    }
#pragma unroll
    for (int t = 0; t < 4; ++t) {
        wp->b2p[t]  = __floats2half2_rn(cs2[2 * t], cs2[2 * t + 1]);
        wp->b3p[t]  = __floats2half2_rn(cs3[2 * t], cs3[2 * t + 1]);
        wp->g1p[t]  = __floats2half2_rn(K2LOG2E * g1[2 * t],  K2LOG2E * g1[2 * t + 1]);
        wp->be1p[t] = __floats2half2_rn(K2LOG2E * be1[2 * t], K2LOG2E * be1[2 * t + 1]);
        wp->g2p[t]  = __floats2half2_rn(K2LOG2E * g2[2 * t],  K2LOG2E * g2[2 * t + 1]);
        wp->be2p[t] = __floats2half2_rn(K2LOG2E * be2[2 * t], K2LOG2E * be2[2 * t + 1]);
        wp->g3p[t]  = __floats2half2_rn(K2LOG2E * g3[2 * t],  K2LOG2E * g3[2 * t + 1]);
        wp->be3p[t] = __floats2half2_rn(K2LOG2E * be3[2 * t], K2LOG2E * be3[2 * t + 1]);
    }
    float sw4 = 0.0f;
#pragma unroll
    for (int i = 0; i < 8; ++i) { wp->w4[i] = -2.0f * W4[i]; sw4 += W4[i]; }
    wp->b4a = b4[0] + sw4;
}

// ---------------- Kernel B: per-edge MLP, 2 edges/thread ---------------------
// site: u = rcp(exp2(arg) + 1); tanh = 1 - 2u is folded into next layer.
__device__ __forceinline__ void site_pair(__half2 arg, float& u0, float& u1) {
    float a0 = __low2float(arg);
    float a1 = __high2float(arg);
    u0 = __builtin_amdgcn_rcpf(EXP2F(a0) + 1.0f);
    u1 = __builtin_amdgcn_rcpf(EXP2F(a1) + 1.0f);
}

__global__ __launch_bounds__(256) void edge_main_kernel(
    const int* __restrict__ ei,       // [2,E]
    const uint4* __restrict__ ya16,   // [N] (8 fp16 each)
    const uint4* __restrict__ yb16,   // [N]
    const WPack* __restrict__ wp,
    float* __restrict__ out, int E)
{
    int tid = blockIdx.x * blockDim.x + threadIdx.x;
    int base = tid * 2;
    if (base >= E) return;

    int s[2], t[2];
    bool dual = (base + 1 < E);
    if (dual) {
        int2 r0 = *reinterpret_cast<const int2*>(ei + base);
        int2 r1 = *reinterpret_cast<const int2*>(ei + E + base);
        s[0] = r0.x; s[1] = r0.y;
        t[0] = r1.x; t[1] = r1.y;
    } else {
        s[0] = ei[base]; t[0] = ei[E + base];
        s[1] = s[0];     t[1] = t[0];
    }

    // gathers (4 independent 16B loads)
    uint4 ua[2], ub[2];
#pragma unroll
    for (int c = 0; c < 2; ++c) { ua[c] = ya16[s[c]]; ub[c] = yb16[t[c]]; }

    __half2 v[2][4];
#pragma unroll
    for (int c = 0; c < 2; ++c) {
        const __half2* ha = reinterpret_cast<const __half2*>(&ua[c]);
        const __half2* hb2 = reinterpret_cast<const __half2*>(&ub[c]);
#pragma unroll
        for (int k = 0; k < 4; ++k) v[c][k] = __hadd2(ha[k], hb2[k]);
    }

    // ---- LN1 (pre-centered) ----
    __half2 rr2[2];
#pragma unroll
    for (int c = 0; c < 2; ++c) {
        __half2 s2 = __hmul2(v[c][0], v[c][0]);
        s2 = __hfma2(v[c][1], v[c][1], s2);
        s2 = __hfma2(v[c][2], v[c][2], s2);
        s2 = __hfma2(v[c][3], v[c][3], s2);
        float ss = __low2float(s2) + __high2float(s2);
        float r = __builtin_amdgcn_rsqf(fmaf(ss, 0.125f, 1e-5f));
        rr2[c] = __floats2half2_rn(r, r);
    }

    // ---- LN1 sites -> u broadcast pairs ----
    __half2 hb[2][8];
#pragma unroll
    for (int c = 0; c < 2; ++c) {
#pragma unroll
        for (int k = 0; k < 4; ++k) {
            __half2 rg  = __hmul2(rr2[c], wp->g1p[k]);
            __half2 arg = __hfma2(v[c][k], rg, wp->be1p[k]);
            float u0, u1;
            site_pair(arg, u0, u1);
            hb[c][2 * k]     = __floats2half2_rn(u0, u0);
            hb[c][2 * k + 1] = __floats2half2_rn(u1, u1);
        }
    }

    // ---- layer 2 (packed fp16, folded weights) ----
    __half2 acc[2][4];
#pragma unroll
    for (int c = 0; c < 2; ++c)
#pragma unroll
        for (int k = 0; k < 4; ++k) acc[c][k] = wp->b2p[k];
#pragma unroll
    for (int i = 0; i < 8; ++i) {
#pragma unroll
        for (int c = 0; c < 2; ++c)
#pragma unroll
            for (int k = 0; k < 4; ++k)
                acc[c][k] = __hfma2(hb[c][i], wp->w2[i * 4 + k], acc[c][k]);
    }

    // ---- LN2 + sites ----
#pragma unroll
    for (int c = 0; c < 2; ++c) {
        __half2 sm2 = __hadd2(__hadd2(acc[c][0], acc[c][1]),
                              __hadd2(acc[c][2], acc[c][3]));
        __half2 sq2 = __hmul2(acc[c][0], acc[c][0]);
        sq2 = __hfma2(acc[c][1], acc[c][1], sq2);
        sq2 = __hfma2(acc[c][2], acc[c][2], sq2);
        sq2 = __hfma2(acc[c][3], acc[c][3], sq2);
        float sm = __low2float(sm2) + __high2float(sm2);
        float sq = __low2float(sq2) + __high2float(sq2);
        float mu = sm * 0.125f;
        float var = fmaf(sq, 0.125f, -mu * mu);
        float rr = __builtin_amdgcn_rsqf(var + 1e-5f);
        __half2 rrp = __floats2half2_rn(rr, rr);
        float m = -mu * rr;
        __half2 mm2 = __floats2half2_rn(m, m);
#pragma unroll
        for (int k = 0; k < 4; ++k) {
            __half2 rg  = __hmul2(rrp, wp->g2p[k]);
            __half2 cc  = __hfma2(mm2, wp->g2p[k], wp->be2p[k]);
            __half2 arg = __hfma2(acc[c][k], rg, cc);
            float u0, u1;
            site_pair(arg, u0, u1);
            hb[c][2 * k]     = __floats2half2_rn(u0, u0);
            hb[c][2 * k + 1] = __floats2half2_rn(u1, u1);
        }
    }

    // ---- layer 3 (packed fp16, folded weights) ----
#pragma unroll
    for (int c = 0; c < 2; ++c)
#pragma unroll
        for (int k = 0; k < 4; ++k) acc[c][k] = wp->b3p[k];
#pragma unroll
    for (int i = 0; i < 8; ++i) {
#pragma unroll
        for (int c = 0; c < 2; ++c)
#pragma unroll
            for (int k = 0; k < 4; ++k)
                acc[c][k] = __hfma2(hb[c][i], wp->w3[i * 4 + k], acc[c][k]);
    }

    // ---- LN3 + sites -> u floats -> layer 4 (fp32, folded) ----
    float o[2];
#pragma unroll
    for (int c = 0; c < 2; ++c) {
        __half2 sm2 = __hadd2(__hadd2(acc[c][0], acc[c][1]),
                              __hadd2(acc[c][2], acc[c][3]));
        __half2 sq2 = __hmul2(acc[c][0], acc[c][0]);
        sq2 = __hfma2(acc[c][1], acc[c][1], sq2);
        sq2 = __hfma2(acc[c][2], acc[c][2], sq2);
        sq2 = __hfma2(acc[c][3], acc[c][3], sq2);
        float sm = __low2float(sm2) + __high2float(sm2);
        float sq = __low2float(sq2) + __high2float(sq2);
        float mu = sm * 0.125f;
        float var = fmaf(sq, 0.125f, -mu * mu);
        float rr = __builtin_amdgcn_rsqf(var + 1e-5f);
        __half2 rrp = __floats2half2_rn(rr, rr);
        float m = -mu * rr;
        __half2 mm2 = __floats2half2_rn(m, m);
        float oo = wp->b4a;
#pragma unroll
        for (int k = 0; k < 4; ++k) {
            __half2 rg  = __hmul2(rrp, wp->g3p[k]);
            __half2 cc  = __hfma2(mm2, wp->g3p[k], wp->be3p[k]);
            __half2 arg = __hfma2(acc[c][k], rg, cc);
            float u0, u1;
            site_pair(arg, u0, u1);
            oo = fmaf(u0, wp->w4[2 * k], oo);
            oo = fmaf(u1, wp->w4[2 * k + 1], oo);
        }
        o[c] = oo;
    }

    if (dual) {
        *reinterpret_cast<float2*>(out + base) = make_float2(o[0], o[1]);
    } else {
        out[base] = o[0];
    }
}

// ---------------- Fallback: monolithic fp32 (only if ws too small) ----------
__device__ __forceinline__ void ln_tanh8_full(float* h, const float* __restrict__ g,
                                              const float* __restrict__ be) {
    float sm = 0.0f, sq = 0.0f;
#pragma unroll
    for (int j = 0; j < 8; ++j) { sm += h[j]; sq = fmaf(h[j], h[j], sq); }
    float mu = sm * 0.125f;
    float var = fmaf(sq, 0.125f, -mu * mu);
    float rr = __builtin_amdgcn_rsqf(var + 1e-5f);
#pragma unroll
    for (int j = 0; j < 8; ++j)
        h[j] = fast_tanh(fmaf(h[j] - mu, rr * g[j], be[j]));
}

__global__ __launch_bounds__(256) void edge_net_fallback(
    const float* __restrict__ x, const int* __restrict__ ei,
    const float* __restrict__ vp, const int* __restrict__ batch,
    const float* __restrict__ W1, const float* __restrict__ b1,
    const float* __restrict__ g1, const float* __restrict__ be1,
    const float* __restrict__ W2, const float* __restrict__ b2,
    const float* __restrict__ g2, const float* __restrict__ be2,
    const float* __restrict__ W3, const float* __restrict__ b3,
    const float* __restrict__ g3, const float* __restrict__ be3,
    const float* __restrict__ W4, const float* __restrict__ b4,
    float* __restrict__ out, int E)
{
    int e = blockIdx.x * blockDim.x + threadIdx.x;
    if (e >= E) return;
    int s = ei[e], t = ei[E + e];
    int gb = batch[s];
    float in[48];
    const float4* ps = reinterpret_cast<const float4*>(x) + (size_t)s * 4;
    const float4* pt = reinterpret_cast<const float4*>(x) + (size_t)t * 4;
    const float4* pv = reinterpret_cast<const float4*>(vp) + (size_t)gb * 4;
#pragma unroll
    for (int q = 0; q < 4; ++q) {
        float4 a = ps[q];
        in[q*4+0]=a.x; in[q*4+1]=a.y; in[q*4+2]=a.z; in[q*4+3]=a.w;
    }
#pragma unroll
    for (int q = 0; q < 4; ++q) {
        float4 a = pt[q];
        in[16+q*4+0]=a.x; in[16+q*4+1]=a.y; in[16+q*4+2]=a.z; in[16+q*4+3]=a.w;
    }
#pragma unroll
    for (int q = 0; q < 4; ++q) {
        float4 a = pv[q];
        in[32+q*4+0]=a.x; in[32+q*4+1]=a.y; in[32+q*4+2]=a.z; in[32+q*4+3]=a.w;
    }
    float h[8];
#pragma unroll
    for (int j = 0; j < 8; ++j) h[j] = b1[j];
#pragma unroll
    for (int i = 0; i < 48; ++i) {
        float v = in[i];
#pragma unroll
        for (int j = 0; j < 8; ++j) h[j] = fmaf(v, W1[i*8+j], h[j]);
    }
    ln_tanh8_full(h, g1, be1);
    float h2[8];
#pragma unroll
    for (int j = 0; j < 8; ++j) h2[j] = b2[j];
#pragma unroll
    for (int i = 0; i < 8; ++i) {
        float v = h[i];
#pragma unroll
        for (int j = 0; j < 8; ++j) h2[j] = fmaf(v, W2[i*8+j], h2[j]);
    }
    ln_tanh8_full(h2, g2, be2);
    float h3[8];
#pragma unroll
    for (int j = 0; j < 8; ++j) h3[j] = b3[j];
#pragma unroll
    for (int i = 0; i < 8; ++i) {
        float v = h2[i];
#pragma unroll
        for (int j = 0; j < 8; ++j) h3[j] = fmaf(v, W3[i*8+j], h3[j]);
    }
    ln_tanh8_full(h3, g3, be3);
    float o = b4[0];
#pragma unroll
    for (int i = 0; i < 8; ++i) o = fmaf(h3[i], W4[i], o);
    out[e] = o;
}

extern "C" void kernel_launch(void* const* d_in, const int* in_sizes, int n_in,
                              void* d_out, int out_size, void* d_ws, size_t ws_size,
                              hipStream_t stream) {
    const float* x     = (const float*)d_in[0];
    const int*   ei    = (const int*)d_in[1];
    const float* vp    = (const float*)d_in[2];
    const int*   batch = (const int*)d_in[3];
    const float* W1  = (const float*)d_in[4];
    const float* b1  = (const float*)d_in[5];
    const float* g1  = (const float*)d_in[6];
    const float* be1 = (const float*)d_in[7];
    const float* W2  = (const float*)d_in[8];
    const float* b2  = (const float*)d_in[9];
    const float* g2  = (const float*)d_in[10];
    const float* be2 = (const float*)d_in[11];
    const float* W3  = (const float*)d_in[12];
    const float* b3  = (const float*)d_in[13];
    const float* g3  = (const float*)d_in[14];
    const float* be3 = (const float*)d_in[15];
    const float* W4  = (const float*)d_in[16];
    const float* b4  = (const float*)d_in[17];

    int E = in_sizes[1] / 2;    // edge_index [2,E]
    int N = in_sizes[3];        // batch [N]
    float* out = (float*)d_out;

    size_t tab_bytes = (size_t)N * 8 * sizeof(_Float16);   // 1.6 MB per table
    size_t need = 2 * tab_bytes + sizeof(WPack) + 64;
    if (ws_size >= need) {
        h8* ya16 = (h8*)d_ws;
        h8* yb16 = (h8*)((char*)d_ws + tab_bytes);
        WPack* wp = (WPack*)((char*)d_ws + 2 * tab_bytes);

        int blockA = 256;
        int gridA = (N + blockA - 1) / blockA;
        hipLaunchKernelGGL(node_pre_kernel, dim3(gridA), dim3(blockA), 0, stream,
                           x, batch, vp, W1, b1, ya16, yb16, N);
        hipLaunchKernelGGL(pack_kernel, dim3(1), dim3(64), 0, stream,
                           W2, b2, W3, b3, g1, be1, g2, be2, g3, be3, W4, b4, wp);
        int pairs = (E + 1) / 2;
        int blockB = 256;
        int gridB = (pairs + blockB - 1) / blockB;
        hipLaunchKernelGGL(edge_main_kernel, dim3(gridB), dim3(blockB), 0, stream,
                           ei, (const uint4*)ya16, (const uint4*)yb16, wp, out, E);
    } else {
        int block = 256;
        int grid = (E + block - 1) / block;
        hipLaunchKernelGGL(edge_net_fallback, dim3(grid), dim3(block), 0, stream,
                           x, ei, vp, batch,
                           W1, b1, g1, be1, W2, b2, g2, be2, W3, b3, g3, be3,
                           W4, b4, out, E);
    }
}

// Round 11
// 144.949 us; speedup vs baseline: 1.0305x; 1.0305x over previous
//
#include <hip/hip_runtime.h>
#include <hip/hip_fp16.h>

// EdgeNetwork: out[e] = MLP(concat(x[s], x[t], vp[batch[s]])), 48->8->8->8->1,
// LayerNorm+tanh between layers.
//
// R9 structure:
//   node_pre (N threads): per-node layer-1 partials, mean-centered, fp16
//     tables ya/yb ([N,8] each, 1.6 MB -> L2-resident). h1 = ya'[s]+yb'[t]
//     is zero-mean -> LN1 skips the mean pass.
//   pack_kernel (1 thread): folds constants:
//     g*, be* scaled by K=2*log2(e)  (tanh arg feeds exp2 directly)
//     W2,W3,W4 -> -2*W ; b -> b + colsum(W)   (tanh = 1 - 2*rcp(exp2+1))
//   edge_main: FOUR edges per thread (R8 post-mortem: 2 chains still
//     latency-bound on the serial site chain cvt->exp->add->rcp->pack).
//     Sites for LN1/LN2 fully in fp16: h2exp2 -> +1 -> h2rcp ->
//     low/high broadcast (no f32 round trip). LN3 sites stay f32 (feed
//     the fp32 output dot). Layers 2/3 in packed fp16 (v_pk_fma_f16).

struct WPack {
    __half2 w2[32];            // -2*W2: w2[i*4+k] = pair (j=2k, 2k+1)
    __half2 w3[32];            // -2*W3
    __half2 b2p[4], b3p[4];    // b + colsum(W)
    __half2 g1p[4], be1p[4];   // g1*K, be1*K
    __half2 g2p[4], be2p[4];
    __half2 g3p[4], be3p[4];
    float w4[8];               // -2*W4
    float b4a;                 // b4 + sum(W4)
};

typedef __attribute__((ext_vector_type(8))) _Float16 h8;

#define K2LOG2E 2.8853900817779268f

__device__ __forceinline__ float fast_tanh(float v) {
    float e = __expf(2.0f * v);
    return fmaf(-2.0f, __builtin_amdgcn_rcpf(e + 1.0f), 1.0f);
}

// ---------------- Kernel A: per-node layer-1 partials (fp16, centered) -------
__global__ __launch_bounds__(256) void node_pre_kernel(
    const float* __restrict__ x,      // [N,16]
    const int* __restrict__ batch,    // [N]
    const float* __restrict__ vp,     // [64,16]
    const float* __restrict__ W1,     // [48,8]
    const float* __restrict__ b1,     // [8]
    h8* __restrict__ ya16,            // [N]
    h8* __restrict__ yb16,            // [N]
    int N)
{
    int n = blockIdx.x * blockDim.x + threadIdx.x;
    if (n >= N) return;

    const float4* px = reinterpret_cast<const float4*>(x) + (size_t)n * 4;
    float4 x0 = px[0], x1 = px[1], x2 = px[2], x3 = px[3];
    int g = batch[n];
    const float4* pv = reinterpret_cast<const float4*>(vp) + (size_t)g * 4;
    float4 v0 = pv[0], v1 = pv[1], v2 = pv[2], v3 = pv[3];

    float xs[16] = {x0.x, x0.y, x0.z, x0.w, x1.x, x1.y, x1.z, x1.w,
                    x2.x, x2.y, x2.z, x2.w, x3.x, x3.y, x3.z, x3.w};
    float vs[16] = {v0.x, v0.y, v0.z, v0.w, v1.x, v1.y, v1.z, v1.w,
                    v2.x, v2.y, v2.z, v2.w, v3.x, v3.y, v3.z, v3.w};

    float ya[8], yb[8];
#pragma unroll
    for (int j = 0; j < 8; ++j) { ya[j] = b1[j]; yb[j] = 0.0f; }

#pragma unroll
    for (int i = 0; i < 16; ++i) {
        float vx = xs[i];
        float vv = vs[i];
#pragma unroll
        for (int j = 0; j < 8; ++j) {
            ya[j] = fmaf(vx, W1[i * 8 + j], ya[j]);
            ya[j] = fmaf(vv, W1[(32 + i) * 8 + j], ya[j]);
            yb[j] = fmaf(vx, W1[(16 + i) * 8 + j], yb[j]);
        }
    }

    float mua = 0.0f, mub = 0.0f;
#pragma unroll
    for (int j = 0; j < 8; ++j) { mua += ya[j]; mub += yb[j]; }
    mua *= 0.125f; mub *= 0.125f;

    h8 va, vb;
#pragma unroll
    for (int j = 0; j < 8; ++j) {
        va[j] = (_Float16)(ya[j] - mua);
        vb[j] = (_Float16)(yb[j] - mub);
    }
    ya16[n] = va;
    yb16[n] = vb;
}

// ---------------- Kernel P: fold + pack constants (1 thread) -----------------
__global__ void pack_kernel(
    const float* __restrict__ W2, const float* __restrict__ b2,
    const float* __restrict__ W3, const float* __restrict__ b3,
    const float* __restrict__ g1, const float* __restrict__ be1,
    const float* __restrict__ g2, const float* __restrict__ be2,
    const float* __restrict__ g3, const float* __restrict__ be3,
    const float* __restrict__ W4, const float* __restrict__ b4,
    WPack* __restrict__ wp)
{
    if (threadIdx.x != 0 || blockIdx.x != 0) return;
#pragma unroll
    for (int t = 0; t < 32; ++t) {
        wp->w2[t] = __floats2half2_rn(-2.0f * W2[2 * t], -2.0f * W2[2 * t + 1]);
        wp->w3[t] = __floats2half2_rn(-2.0f * W3[2 * t], -2.0f * W3[2 * t + 1]);
    }
    float cs2[8], cs3[8];
#pragma unroll
    for (int j = 0; j < 8; ++j) {
        float s2 = 0.0f, s3 = 0.0f;
#pragma unroll
        for (int i = 0; i < 8; ++i) { s2 += W2[i * 8 + j]; s3 += W3[i * 8 + j]; }
        cs2[j] = b2[j] + s2;
        cs3[j] = b3[j] + s3;
    }
#pragma unroll
    for (int t = 0; t < 4; ++t) {
        wp->b2p[t]  = __floats2half2_rn(cs2[2 * t], cs2[2 * t + 1]);
        wp->b3p[t]  = __floats2half2_rn(cs3[2 * t], cs3[2 * t + 1]);
        wp->g1p[t]  = __floats2half2_rn(K2LOG2E * g1[2 * t],  K2LOG2E * g1[2 * t + 1]);
        wp->be1p[t] = __floats2half2_rn(K2LOG2E * be1[2 * t], K2LOG2E * be1[2 * t + 1]);
        wp->g2p[t]  = __floats2half2_rn(K2LOG2E * g2[2 * t],  K2LOG2E * g2[2 * t + 1]);
        wp->be2p[t] = __floats2half2_rn(K2LOG2E * be2[2 * t], K2LOG2E * be2[2 * t + 1]);
        wp->g3p[t]  = __floats2half2_rn(K2LOG2E * g3[2 * t],  K2LOG2E * g3[2 * t + 1]);
        wp->be3p[t] = __floats2half2_rn(K2LOG2E * be3[2 * t], K2LOG2E * be3[2 * t + 1]);
    }
    float sw4 = 0.0f;
#pragma unroll
    for (int i = 0; i < 8; ++i) { wp->w4[i] = -2.0f * W4[i]; sw4 += W4[i]; }
    wp->b4a = b4[0] + sw4;
}

// ---------------- Kernel B: per-edge MLP, 4 edges/thread ---------------------
#define NC 4

// fp16 site: u = rcp(exp2(arg)+1), broadcast each half. (~7 instrs/pair)
__device__ __forceinline__ void site_h2(__half2 arg, __half2& o0, __half2& o1) {
    __half2 e = h2exp2(arg);
    __half2 u = h2rcp(__hadd2(e, __float2half2_rn(1.0f)));
    o0 = __low2half2(u);
    o1 = __high2half2(u);
}

__global__ __launch_bounds__(256) void edge_main_kernel(
    const int* __restrict__ ei,       // [2,E]
    const uint4* __restrict__ ya16,   // [N] (8 fp16 each)
    const uint4* __restrict__ yb16,   // [N]
    const WPack* __restrict__ wp,
    float* __restrict__ out, int E)
{
    int tid = blockIdx.x * blockDim.x + threadIdx.x;
    int base = tid * NC;
    if (base >= E) return;
    bool full = (base + NC - 1 < E);

    int s[NC], t[NC];
    if (full) {
        int4 r0 = *reinterpret_cast<const int4*>(ei + base);
        int4 r1 = *reinterpret_cast<const int4*>(ei + E + base);
        s[0] = r0.x; s[1] = r0.y; s[2] = r0.z; s[3] = r0.w;
        t[0] = r1.x; t[1] = r1.y; t[2] = r1.z; t[3] = r1.w;
    } else {
#pragma unroll
        for (int c = 0; c < NC; ++c) {
            int e = base + c < E ? base + c : E - 1;
            s[c] = ei[e]; t[c] = ei[E + e];
        }
    }

    // gathers (2*NC independent 16B loads)
    uint4 ua[NC], ub[NC];
#pragma unroll
    for (int c = 0; c < NC; ++c) { ua[c] = ya16[s[c]]; ub[c] = yb16[t[c]]; }

    __half2 v[NC][4];
#pragma unroll
    for (int c = 0; c < NC; ++c) {
        const __half2* ha = reinterpret_cast<const __half2*>(&ua[c]);
        const __half2* hbb = reinterpret_cast<const __half2*>(&ub[c]);
#pragma unroll
        for (int k = 0; k < 4; ++k) v[c][k] = __hadd2(ha[k], hbb[k]);
    }

    // ---- LN1 (pre-centered) ----
    __half2 rr2[NC];
#pragma unroll
    for (int c = 0; c < NC; ++c) {
        __half2 s2 = __hmul2(v[c][0], v[c][0]);
        s2 = __hfma2(v[c][1], v[c][1], s2);
        s2 = __hfma2(v[c][2], v[c][2], s2);
        s2 = __hfma2(v[c][3], v[c][3], s2);
        float ss = __low2float(s2) + __high2float(s2);
        float r = __builtin_amdgcn_rsqf(fmaf(ss, 0.125f, 1e-5f));
        rr2[c] = __floats2half2_rn(r, r);
    }

    // ---- LN1 sites -> u broadcast pairs (fp16 path) ----
    __half2 hb[NC][8];
#pragma unroll
    for (int k = 0; k < 4; ++k) {
#pragma unroll
        for (int c = 0; c < NC; ++c) {
            __half2 rg  = __hmul2(rr2[c], wp->g1p[k]);
            __half2 arg = __hfma2(v[c][k], rg, wp->be1p[k]);
            site_h2(arg, hb[c][2 * k], hb[c][2 * k + 1]);
        }
    }

    // ---- layer 2 (packed fp16, folded weights) ----
    __half2 acc[NC][4];
#pragma unroll
    for (int c = 0; c < NC; ++c)
#pragma unroll
        for (int k = 0; k < 4; ++k) acc[c][k] = wp->b2p[k];
#pragma unroll
    for (int i = 0; i < 8; ++i) {
#pragma unroll
        for (int c = 0; c < NC; ++c)
#pragma unroll
            for (int k = 0; k < 4; ++k)
                acc[c][k] = __hfma2(hb[c][i], wp->w2[i * 4 + k], acc[c][k]);
    }

    // ---- LN2 + sites (fp16 path) ----
#pragma unroll
    for (int c = 0; c < NC; ++c) {
        __half2 sm2 = __hadd2(__hadd2(acc[c][0], acc[c][1]),
                              __hadd2(acc[c][2], acc[c][3]));
        __half2 sq2 = __hmul2(acc[c][0], acc[c][0]);
        sq2 = __hfma2(acc[c][1], acc[c][1], sq2);
        sq2 = __hfma2(acc[c][2], acc[c][2], sq2);
        sq2 = __hfma2(acc[c][3], acc[c][3], sq2);
        float sm = __low2float(sm2) + __high2float(sm2);
        float sq = __low2float(sq2) + __high2float(sq2);
        float mu = sm * 0.125f;
        float var = fmaf(sq, 0.125f, -mu * mu);
        float rr = __builtin_amdgcn_rsqf(var + 1e-5f);
        __half2 rrp = __floats2half2_rn(rr, rr);
        float m = -mu * rr;
        __half2 mm2 = __floats2half2_rn(m, m);
#pragma unroll
        for (int k = 0; k < 4; ++k) {
            __half2 rg  = __hmul2(rrp, wp->g2p[k]);
            __half2 cc  = __hfma2(mm2, wp->g2p[k], wp->be2p[k]);
            __half2 arg = __hfma2(acc[c][k], rg, cc);
            site_h2(arg, hb[c][2 * k], hb[c][2 * k + 1]);
        }
    }

    // ---- layer 3 (packed fp16, folded weights) ----
#pragma unroll
    for (int c = 0; c < NC; ++c)
#pragma unroll
        for (int k = 0; k < 4; ++k) acc[c][k] = wp->b3p[k];
#pragma unroll
    for (int i = 0; i < 8; ++i) {
#pragma unroll
        for (int c = 0; c < NC; ++c)
#pragma unroll
            for (int k = 0; k < 4; ++k)
                acc[c][k] = __hfma2(hb[c][i], wp->w3[i * 4 + k], acc[c][k]);
    }

    // ---- LN3 + sites (f32, feeds fp32 layer 4) ----
    float o[NC];
#pragma unroll
    for (int c = 0; c < NC; ++c) {
        __half2 sm2 = __hadd2(__hadd2(acc[c][0], acc[c][1]),
                              __hadd2(acc[c][2], acc[c][3]));
        __half2 sq2 = __hmul2(acc[c][0], acc[c][0]);
        sq2 = __hfma2(acc[c][1], acc[c][1], sq2);
        sq2 = __hfma2(acc[c][2], acc[c][2], sq2);
        sq2 = __hfma2(acc[c][3], acc[c][3], sq2);
        float sm = __low2float(sm2) + __high2float(sm2);
        float sq = __low2float(sq2) + __high2float(sq2);
        float mu = sm * 0.125f;
        float var = fmaf(sq, 0.125f, -mu * mu);
        float rr = __builtin_amdgcn_rsqf(var + 1e-5f);
        __half2 rrp = __floats2half2_rn(rr, rr);
        float m = -mu * rr;
        __half2 mm2 = __floats2half2_rn(m, m);
        float oo = wp->b4a;
#pragma unroll
        for (int k = 0; k < 4; ++k) {
            __half2 rg  = __hmul2(rrp, wp->g3p[k]);
            __half2 cc  = __hfma2(mm2, wp->g3p[k], wp->be3p[k]);
            __half2 arg = __hfma2(acc[c][k], rg, cc);
            float a0 = __low2float(arg);
            float a1 = __high2float(arg);
            float u0 = __builtin_amdgcn_rcpf(exp2f(a0) + 1.0f);
            float u1 = __builtin_amdgcn_rcpf(exp2f(a1) + 1.0f);
            oo = fmaf(u0, wp->w4[2 * k], oo);
            oo = fmaf(u1, wp->w4[2 * k + 1], oo);
        }
        o[c] = oo;
    }

    if (full) {
        *reinterpret_cast<float4*>(out + base) = make_float4(o[0], o[1], o[2], o[3]);
    } else {
#pragma unroll
        for (int c = 0; c < NC; ++c)
            if (base + c < E) out[base + c] = o[c];
    }
}

// ---------------- Fallback: monolithic fp32 (only if ws too small) ----------
__device__ __forceinline__ void ln_tanh8_full(float* h, const float* __restrict__ g,
                                              const float* __restrict__ be) {
    float sm = 0.0f, sq = 0.0f;
#pragma unroll
    for (int j = 0; j < 8; ++j) { sm += h[j]; sq = fmaf(h[j], h[j], sq); }
    float mu = sm * 0.125f;
    float var = fmaf(sq, 0.125f, -mu * mu);
    float rr = __builtin_amdgcn_rsqf(var + 1e-5f);
#pragma unroll
    for (int j = 0; j < 8; ++j)
        h[j] = fast_tanh(fmaf(h[j] - mu, rr * g[j], be[j]));
}

__global__ __launch_bounds__(256) void edge_net_fallback(
    const float* __restrict__ x, const int* __restrict__ ei,
    const float* __restrict__ vp, const int* __restrict__ batch,
    const float* __restrict__ W1, const float* __restrict__ b1,
    const float* __restrict__ g1, const float* __restrict__ be1,
    const float* __restrict__ W2, const float* __restrict__ b2,
    const float* __restrict__ g2, const float* __restrict__ be2,
    const float* __restrict__ W3, const float* __restrict__ b3,
    const float* __restrict__ g3, const float* __restrict__ be3,
    const float* __restrict__ W4, const float* __restrict__ b4,
    float* __restrict__ out, int E)
{
    int e = blockIdx.x * blockDim.x + threadIdx.x;
    if (e >= E) return;
    int s = ei[e], t = ei[E + e];
    int gb = batch[s];
    float in[48];
    const float4* ps = reinterpret_cast<const float4*>(x) + (size_t)s * 4;
    const float4* pt = reinterpret_cast<const float4*>(x) + (size_t)t * 4;
    const float4* pv = reinterpret_cast<const float4*>(vp) + (size_t)gb * 4;
#pragma unroll
    for (int q = 0; q < 4; ++q) {
        float4 a = ps[q];
        in[q*4+0]=a.x; in[q*4+1]=a.y; in[q*4+2]=a.z; in[q*4+3]=a.w;
    }
#pragma unroll
    for (int q = 0; q < 4; ++q) {
        float4 a = pt[q];
        in[16+q*4+0]=a.x; in[16+q*4+1]=a.y; in[16+q*4+2]=a.z; in[16+q*4+3]=a.w;
    }
#pragma unroll
    for (int q = 0; q < 4; ++q) {
        float4 a = pv[q];
        in[32+q*4+0]=a.x; in[32+q*4+1]=a.y; in[32+q*4+2]=a.z; in[32+q*4+3]=a.w;
    }
    float h[8];
#pragma unroll
    for (int j = 0; j < 8; ++j) h[j] = b1[j];
#pragma unroll
    for (int i = 0; i < 48; ++i) {
        float v = in[i];
#pragma unroll
        for (int j = 0; j < 8; ++j) h[j] = fmaf(v, W1[i*8+j], h[j]);
    }
    ln_tanh8_full(h, g1, be1);
    float h2[8];
#pragma unroll
    for (int j = 0; j < 8; ++j) h2[j] = b2[j];
#pragma unroll
    for (int i = 0; i < 8; ++i) {
        float v = h[i];
#pragma unroll
        for (int j = 0; j < 8; ++j) h2[j] = fmaf(v, W2[i*8+j], h2[j]);
    }
    ln_tanh8_full(h2, g2, be2);
    float h3[8];
#pragma unroll
    for (int j = 0; j < 8; ++j) h3[j] = b3[j];
#pragma unroll
    for (int i = 0; i < 8; ++i) {
        float v = h2[i];
#pragma unroll
        for (int j = 0; j < 8; ++j) h3[j] = fmaf(v, W3[i*8+j], h3[j]);
    }
    ln_tanh8_full(h3, g3, be3);
    float o = b4[0];
#pragma unroll
    for (int i = 0; i < 8; ++i) o = fmaf(h3[i], W4[i], o);
    out[e] = o;
}

extern "C" void kernel_launch(void* const* d_in, const int* in_sizes, int n_in,
                              void* d_out, int out_size, void* d_ws, size_t ws_size,
                              hipStream_t stream) {
    const float* x     = (const float*)d_in[0];
    const int*   ei    = (const int*)d_in[1];
    const float* vp    = (const float*)d_in[2];
    const int*   batch = (const int*)d_in[3];
    const float* W1  = (const float*)d_in[4];
    const float* b1  = (const float*)d_in[5];
    const float* g1  = (const float*)d_in[6];
    const float* be1 = (const float*)d_in[7];
    const float* W2  = (const float*)d_in[8];
    const float* b2  = (const float*)d_in[9];
    const float* g2  = (const float*)d_in[10];
    const float* be2 = (const float*)d_in[11];
    const float* W3  = (const float*)d_in[12];
    const float* b3  = (const float*)d_in[13];
    const float* g3  = (const float*)d_in[14];
    const float* be3 = (const float*)d_in[15];
    const float* W4  = (const float*)d_in[16];
    const float* b4  = (const float*)d_in[17];

    int E = in_sizes[1] / 2;    // edge_index [2,E]
    int N = in_sizes[3];        // batch [N]
    float* out = (float*)d_out;

    size_t tab_bytes = (size_t)N * 8 * sizeof(_Float16);   // 1.6 MB per table
    size_t need = 2 * tab_bytes + sizeof(WPack) + 64;
    if (ws_size >= need) {
        h8* ya16 = (h8*)d_ws;
        h8* yb16 = (h8*)((char*)d_ws + tab_bytes);
        WPack* wp = (WPack*)((char*)d_ws + 2 * tab_bytes);

        int blockA = 256;
        int gridA = (N + blockA - 1) / blockA;
        hipLaunchKernelGGL(node_pre_kernel, dim3(gridA), dim3(blockA), 0, stream,
                           x, batch, vp, W1, b1, ya16, yb16, N);
        hipLaunchKernelGGL(pack_kernel, dim3(1), dim3(64), 0, stream,
                           W2, b2, W3, b3, g1, be1, g2, be2, g3, be3, W4, b4, wp);
        int groups = (E + NC - 1) / NC;
        int blockB = 256;
        int gridB = (groups + blockB - 1) / blockB;
        hipLaunchKernelGGL(edge_main_kernel, dim3(gridB), dim3(blockB), 0, stream,
                           ei, (const uint4*)ya16, (const uint4*)yb16, wp, out, E);
    } else {
        int block = 256;
        int grid = (E + block - 1) / block;
        hipLaunchKernelGGL(edge_net_fallback, dim3(grid), dim3(block), 0, stream,
                           x, ei, vp, batch,
                           W1, b1, g1, be1, W2, b2, g2, be2, W3, b3, g3, be3,
                           W4, b4, out, E);
    }
}